// Round 1
// baseline (320.158 us; speedup 1.0000x reference)
//
#include <hip/hip_runtime.h>

#define N 4096            // row length (elements)
#define NV (N / 4)        // row length in float4
#define NEG_BIG -9999999.9f

// One wave (64 lanes) per row; 64 elements per lane, all in VGPRs.
// tau found by Newton on f(t) = sum(relu(z - rmax + t)) - 1, which after
// convergence equals the reference's sorted-support formula exactly.
__global__ __launch_bounds__(256, 3)
void sparsemax_kernel(const float* __restrict__ x,
                      const float* __restrict__ m,
                      float* __restrict__ out,
                      int rows) {
    const int lane = threadIdx.x & 63;
    const int wave = threadIdx.x >> 6;
    const int row  = blockIdx.x * 4 + wave;
    if (row >= rows) return;

    const float4* __restrict__ xr = (const float4*)x + (size_t)row * NV;
    const float4* __restrict__ mr = (const float4*)m + (size_t)row * NV;
    float4* __restrict__ outr     = (float4*)out + (size_t)row * NV;

    // Load row: z = (mask ? x : NEG_BIG) * 2   (/(1-TEMP) with TEMP=0.5)
    float z[64];
    float rmax = -3.0e38f;
#pragma unroll
    for (int j = 0; j < 16; ++j) {
        float4 xv = xr[j * 64 + lane];
        float4 mv = mr[j * 64 + lane];
        float z0 = (mv.x != 0.0f ? xv.x : NEG_BIG) * 2.0f;
        float z1 = (mv.y != 0.0f ? xv.y : NEG_BIG) * 2.0f;
        float z2 = (mv.z != 0.0f ? xv.z : NEG_BIG) * 2.0f;
        float z3 = (mv.w != 0.0f ? xv.w : NEG_BIG) * 2.0f;
        z[4 * j + 0] = z0;
        z[4 * j + 1] = z1;
        z[4 * j + 2] = z2;
        z[4 * j + 3] = z3;
        rmax = fmaxf(rmax, fmaxf(fmaxf(z0, z1), fmaxf(z2, z3)));
    }

    // Wave-wide max reduction (butterfly over 64 lanes)
#pragma unroll
    for (int k = 32; k >= 1; k >>= 1)
        rmax = fmaxf(rmax, __shfl_xor(rmax, k, 64));

    // Newton iteration on u = t - rmax  (so v = z + u = (z - rmax) + t).
    // u0 corresponds to t0 = 1 (guarantees f(t0) >= 0, support >= 1).
    float u = 1.0f - rmax;
    for (int it = 0; it < 10; ++it) {
        float s = 0.0f, c = 0.0f;
#pragma unroll
        for (int i = 0; i < 64; ++i) {
            float v = z[i] + u;
            s += fmaxf(v, 0.0f);
            c += (v > 0.0f) ? 1.0f : 0.0f;
        }
#pragma unroll
        for (int k = 32; k >= 1; k >>= 1) {
            s += __shfl_xor(s, k, 64);
            c += __shfl_xor(c, k, 64);
        }
        // t' = t - (f(t)-1)/f'(t); c >= 1 always since t > 0 is invariant
        u -= (s - 1.0f) / c;
    }

    // All-masked row (rmax == 2*NEG_BIG): reference multiplies by mask -> 0.
    const float live = (rmax == NEG_BIG * 2.0f) ? 0.0f : 1.0f;

#pragma unroll
    for (int j = 0; j < 16; ++j) {
        float4 o;
        o.x = fmaxf(z[4 * j + 0] + u, 0.0f) * live;
        o.y = fmaxf(z[4 * j + 1] + u, 0.0f) * live;
        o.z = fmaxf(z[4 * j + 2] + u, 0.0f) * live;
        o.w = fmaxf(z[4 * j + 3] + u, 0.0f) * live;
        outr[j * 64 + lane] = o;
    }
}

extern "C" void kernel_launch(void* const* d_in, const int* in_sizes, int n_in,
                              void* d_out, int out_size, void* d_ws, size_t ws_size,
                              hipStream_t stream) {
    const float* x = (const float*)d_in[0];
    const float* m = (const float*)d_in[1];
    float* out = (float*)d_out;
    const int rows = in_sizes[0] / N;          // 8192
    const int blocks = (rows + 3) / 4;         // 4 rows (waves) per 256-thread block
    sparsemax_kernel<<<blocks, 256, 0, stream>>>(x, m, out, rows);
}